// Round 7
// baseline (319.097 us; speedup 1.0000x reference)
//
#include <hip/hip_runtime.h>
#include <hip/hip_bf16.h>

typedef __attribute__((ext_vector_type(8))) short shortx8;
typedef __attribute__((ext_vector_type(4))) float floatx4;
typedef __attribute__((ext_vector_type(4))) unsigned uintx4;
typedef __attribute__((ext_vector_type(2))) unsigned uintx2;

#define B_ 2
#define T_ 2048
#define D_ 1024
#define H_ 16
#define HD_ 64
#define SCALE 0.125f
#define SMAX 16.0f
#define FULLH ((size_t)B_ * H_ * T_ * HD_)

__device__ __forceinline__ short f2bf(float f) {
    union { float f; unsigned u; } v; v.f = f;
    unsigned r = v.u + 0x7FFFu + ((v.u >> 16) & 1u);
    return (short)(r >> 16);
}

__device__ __forceinline__ unsigned pk2(float x, float y) {
    union { __hip_bfloat162 h; unsigned u; } t;
    t.h = __float22bfloat162_rn(make_float2(x, y));
    return t.u;
}

// load 8 consecutive floats -> 8 bf16
__device__ __forceinline__ shortx8 ldf8_bf(const float* p) {
    const floatx4* q = reinterpret_cast<const floatx4*>(p);
    floatx4 a = q[0], b = q[1];
    uintx4 r = { pk2(a[0], a[1]), pk2(a[2], a[3]), pk2(b[0], b[1]), pk2(b[2], b[3]) };
    return __builtin_bit_cast(shortx8, r);
}

// Q/K/V projection, 128x128 tiles. grid (24,32): bx n-tile (sel = bx/8: 0=q,1=k,2=v),
// by m-tile. Q (scaled) & K head-major [b][h][t][d]; V dim-major [b][h][d][t].
__global__ __launch_bounds__(256) void qkv_gemm(const float* __restrict__ x,
                                                const float* __restrict__ wqkv,
                                                short* __restrict__ qout,
                                                short* __restrict__ kv) {
    __shared__ __align__(16) short As[128][72];
    __shared__ __align__(16) short Bs[128][72];

    const int tid = threadIdx.x;
    const int wv   = tid >> 6;
    const int l    = tid & 63;
    const int ln   = l & 15;
    const int quad = l >> 4;
    const int qd   = quad << 3;
    const int rowb = quad << 2;
    const int wm   = wv >> 1, wn = wv & 1;
    const int m0   = blockIdx.y * 128;
    const int n0g  = blockIdx.x * 128;

    const int srow = tid >> 1;             // staging row 0..127
    const int sch  = (tid & 1) << 5;       // col half 0/32

    floatx4 acc[4][4] = {};

    for (int k0 = 0; k0 < D_; k0 += 64) {
        __syncthreads();
        {
            const float* ap = &x[(size_t)(m0 + srow) * D_ + k0 + sch];
            const float* bp = &wqkv[(size_t)(n0g + srow) * D_ + k0 + sch];
#pragma unroll
            for (int f = 0; f < 4; ++f)
                *reinterpret_cast<shortx8*>(&As[srow][sch + f * 8]) = ldf8_bf(ap + f * 8);
#pragma unroll
            for (int f = 0; f < 4; ++f)
                *reinterpret_cast<shortx8*>(&Bs[srow][sch + f * 8]) = ldf8_bf(bp + f * 8);
        }
        __syncthreads();

#pragma unroll
        for (int kk = 0; kk < 2; ++kk) {
            shortx8 af[4], bf[4];
#pragma unroll
            for (int i = 0; i < 4; ++i)
                af[i] = *reinterpret_cast<const shortx8*>(&As[wm * 64 + i * 16 + ln][kk * 32 + qd]);
#pragma unroll
            for (int j = 0; j < 4; ++j)
                bf[j] = *reinterpret_cast<const shortx8*>(&Bs[wn * 64 + j * 16 + ln][kk * 32 + qd]);
#pragma unroll
            for (int i = 0; i < 4; ++i)
#pragma unroll
                for (int j = 0; j < 4; ++j)
                    acc[i][j] = __builtin_amdgcn_mfma_f32_16x16x32_bf16(af[i], bf[j], acc[i][j], 0, 0, 0);
        }
    }

    const int sel = n0g >> 10;
    const int bb  = m0 >> 11;
    const int t0w = (m0 + wm * 64) & (T_ - 1);
    const int h   = ((n0g + wn * 64) >> 6) & 15;

    if (sel < 2) {
        short* dst = (sel == 0) ? qout : kv;
        const float sc = (sel == 0) ? SCALE : 1.0f;
        const size_t hbase = (size_t)(bb * H_ + h) * T_;
#pragma unroll
        for (int i = 0; i < 4; ++i) {
#pragma unroll
            for (int r = 0; r < 4; ++r) {
                int t = t0w + i * 16 + rowb + r;
#pragma unroll
                for (int j = 0; j < 4; ++j)
                    dst[(hbase + t) * HD_ + j * 16 + ln] = f2bf(acc[i][j][r] * sc);
            }
        }
    } else {
        // V: transpose via per-wave LDS buffer (As/Bs dead)
        __syncthreads();
        short* tb = (wv < 2) ? &As[wv * 64][0] : &Bs[(wv - 2) * 64][0];  // 64 x 72
#pragma unroll
        for (int i = 0; i < 4; ++i)
#pragma unroll
            for (int j = 0; j < 4; ++j)
#pragma unroll
                for (int r = 0; r < 4; ++r)
                    tb[(j * 16 + ln) * 72 + i * 16 + rowb + r] = f2bf(acc[i][j][r]);
        __syncthreads();
        // lane l owns dim d=l: write 64 t-values (contiguous) to [b][h][d][t]
        short* vdst = kv + FULLH + ((size_t)(bb * H_ + h) * HD_ + l) * T_ + t0w;
#pragma unroll
        for (int seg = 0; seg < 8; ++seg)
            *reinterpret_cast<shortx8*>(vdst + seg * 8) =
                *reinterpret_cast<const shortx8*>(&tb[l * 72 + seg * 8]);
    }
}

// Flash attention (causal + ALiBi), fixed-max softmax, 128-query blocks.
// grid 512: qb = 15-(bx&15) (heavy first), h=(bx>>4)&15, b=bx>>8.
// Each wave owns two 16-row Q-subtiles (qt=0/1) sharing staged K/V.
__global__ __launch_bounds__(256, 4) void attn(const short* __restrict__ qws,
                                               const short* __restrict__ kv,
                                               short* ao) {
    __shared__ __align__(16) short Ks[64][72];
    __shared__ __align__(16) short Vt[64][72];      // Vt[d][key]
    __shared__ __align__(16) short Pt[4][64][20];   // per-wave [key][qrow+pad]

    const int tid = threadIdx.x;
    const int wv   = tid >> 6;
    const int l    = tid & 63;
    const int ln   = l & 15;
    const int quad = l >> 4;
    const int qd   = quad << 3;
    const int rowb = quad << 2;

    const int qb = 15 - (blockIdx.x & 15);
    const int h  = (blockIdx.x >> 4) & 15;
    const int b  = blockIdx.x >> 8;

    const float slope = exp2f(-(float)(h + 1) * (1.0f / 16.0f));
    const size_t koff = (size_t)(b * H_ + h) * T_ * HD_;

    // two Q-subtiles: rows rowq0[qt] .. +4 (this lane's quad rows)
    int rowq0[2];
    rowq0[0] = qb * 128 + wv * 16 + rowb;
    rowq0[1] = rowq0[0] + 64;

    shortx8 qf[2][2];
#pragma unroll
    for (int qt = 0; qt < 2; ++qt)
#pragma unroll
        for (int kk = 0; kk < 2; ++kk)
            qf[qt][kk] = *reinterpret_cast<const shortx8*>(
                &qws[koff + (size_t)(qb * 128 + qt * 64 + wv * 16 + ln) * HD_ + kk * 32 + qd]);

    const int r0 = tid >> 3, c0 = (tid & 7) << 3, r1 = r0 + 32;
    const short* kbase = kv + koff;
    const short* vbase = kv + FULLH + koff;
    shortx8 kA, kB, vA, vB;
    auto FETCH = [&](int kb) {
        const short* kp = kbase + ((size_t)(kb * 64) << 6);
        kA = *reinterpret_cast<const shortx8*>(kp + ((size_t)r0 << 6) + c0);
        kB = *reinterpret_cast<const shortx8*>(kp + ((size_t)r1 << 6) + c0);
        const short* vp = vbase + kb * 64;
        vA = *reinterpret_cast<const shortx8*>(vp + ((size_t)r0 << 11) + c0);
        vB = *reinterpret_cast<const shortx8*>(vp + ((size_t)r1 << 11) + c0);
    };

    floatx4 oacc[2][4] = {};
    floatx4 lsum[2] = {};
    const shortx8 ones = {16256, 16256, 16256, 16256, 16256, 16256, 16256, 16256};
    const int kbmax = 2 * qb + 1;

    FETCH(0);
    for (int kb = 0; kb <= kbmax; ++kb) {
        __syncthreads();
        *reinterpret_cast<shortx8*>(&Ks[r0][c0]) = kA;
        *reinterpret_cast<shortx8*>(&Ks[r1][c0]) = kB;
        *reinterpret_cast<shortx8*>(&Vt[r0][c0]) = vA;
        *reinterpret_cast<shortx8*>(&Vt[r1][c0]) = vB;
        __syncthreads();
        if (kb < kbmax) FETCH(kb + 1);

        const int kln = kb * 64 + ln;

#pragma unroll
        for (int qt = 0; qt < 2; ++qt) {
            const int qtb = 2 * qb + qt;
            if (kb > qtb) continue;
            const bool diag = (kb == qtb);
            const int ncmax = diag ? (wv + 1) : 4;
            const float bb0 = slope * (float)kln - SMAX - slope * (float)rowq0[qt];

#pragma unroll
            for (int nc = 0; nc < 4; ++nc) {
                floatx4 s = {};
                if (nc < ncmax) {
#pragma unroll
                    for (int kk = 0; kk < 2; ++kk) {
                        shortx8 bfr = *reinterpret_cast<const shortx8*>(&Ks[nc * 16 + ln][kk * 32 + qd]);
                        s = __builtin_amdgcn_mfma_f32_16x16x32_bf16(qf[qt][kk], bfr, s, 0, 0, 0);
                    }
                }
                float p[4];
#pragma unroll
                for (int r = 0; r < 4; ++r) {
                    bool ok = (kln + nc * 16) <= (rowq0[qt] + r);
                    float e = __expf(s[r] + bb0 + slope * (float)(nc * 16 - r));
                    p[r] = ok ? e : 0.0f;
                }
                uintx2 pkd = { pk2(p[0], p[1]), pk2(p[2], p[3]) };
                *reinterpret_cast<uintx2*>(&Pt[wv][nc * 16 + ln][rowb]) = pkd;
            }

#pragma unroll
            for (int kk = 0; kk < 2; ++kk) {
                if (diag && kk * 32 > wv * 16 + 15) continue;
                shortx8 pf;
#pragma unroll
                for (int j = 0; j < 8; ++j) pf[j] = Pt[wv][kk * 32 + qd + j][ln];
                lsum[qt] = __builtin_amdgcn_mfma_f32_16x16x32_bf16(pf, ones, lsum[qt], 0, 0, 0);
#pragma unroll
                for (int nc = 0; nc < 4; ++nc) {
                    shortx8 bfr = *reinterpret_cast<const shortx8*>(&Vt[nc * 16 + ln][kk * 32 + qd]);
                    oacc[qt][nc] = __builtin_amdgcn_mfma_f32_16x16x32_bf16(pf, bfr, oacc[qt][nc], 0, 0, 0);
                }
            }
        }
    }

#pragma unroll
    for (int qt = 0; qt < 2; ++qt) {
#pragma unroll
        for (int r = 0; r < 4; ++r) {
            float inv = 1.0f / lsum[qt][r];
            int t = rowq0[qt] + r;
#pragma unroll
            for (int nc = 0; nc < 4; ++nc)
                ao[koff + (size_t)t * HD_ + nc * 16 + ln] = f2bf(oacc[qt][nc][r] * inv);
        }
    }
}

// Final projection, 128x128 tiles: out(fp32) = attn_out(bf16 head-major) @ w_out(fp32)^T
__global__ __launch_bounds__(256) void out_gemm(const short* __restrict__ A,
                                                const float* __restrict__ W,
                                                float* __restrict__ out) {
    __shared__ __align__(16) short As[128][72];
    __shared__ __align__(16) short Bs[128][72];

    const int tid = threadIdx.x;
    const int wv   = tid >> 6;
    const int l    = tid & 63;
    const int ln   = l & 15;
    const int quad = l >> 4;
    const int qd   = quad << 3;
    const int rowb = quad << 2;
    const int wm   = wv >> 1, wn = wv & 1;
    const int m0   = blockIdx.y * 128;
    const int n0g  = blockIdx.x * 128;

    const int srow = tid >> 1;
    const int sch  = (tid & 1) << 5;

    floatx4 acc[4][4] = {};

    for (int k0 = 0; k0 < D_; k0 += 64) {
        const int h = k0 >> 6;
        __syncthreads();
        {
            int m = m0 + srow;
            int bb = m >> 11, t = m & (T_ - 1);
            const short* ap = A + ((size_t)(bb * H_ + h) * T_ + t) * HD_ + sch;
            const float* bp = &W[(size_t)(n0g + srow) * D_ + k0 + sch];
#pragma unroll
            for (int f = 0; f < 4; ++f)
                *reinterpret_cast<shortx8*>(&As[srow][sch + f * 8]) =
                    *reinterpret_cast<const shortx8*>(ap + f * 8);
#pragma unroll
            for (int f = 0; f < 4; ++f)
                *reinterpret_cast<shortx8*>(&Bs[srow][sch + f * 8]) = ldf8_bf(bp + f * 8);
        }
        __syncthreads();

#pragma unroll
        for (int kk = 0; kk < 2; ++kk) {
            shortx8 af[4], bf[4];
#pragma unroll
            for (int i = 0; i < 4; ++i)
                af[i] = *reinterpret_cast<const shortx8*>(&As[wm * 64 + i * 16 + ln][kk * 32 + qd]);
#pragma unroll
            for (int j = 0; j < 4; ++j)
                bf[j] = *reinterpret_cast<const shortx8*>(&Bs[wn * 64 + j * 16 + ln][kk * 32 + qd]);
#pragma unroll
            for (int i = 0; i < 4; ++i)
#pragma unroll
                for (int j = 0; j < 4; ++j)
                    acc[i][j] = __builtin_amdgcn_mfma_f32_16x16x32_bf16(af[i], bf[j], acc[i][j], 0, 0, 0);
        }
    }

#pragma unroll
    for (int i = 0; i < 4; ++i) {
#pragma unroll
        for (int r = 0; r < 4; ++r) {
            int m = m0 + wm * 64 + i * 16 + rowb + r;
#pragma unroll
            for (int j = 0; j < 4; ++j)
                out[(size_t)m * D_ + n0g + wn * 64 + j * 16 + ln] = acc[i][j][r];
        }
    }
}

extern "C" void kernel_launch(void* const* d_in, const int* in_sizes, int n_in,
                              void* d_out, int out_size, void* d_ws, size_t ws_size,
                              hipStream_t stream) {
    const float* x    = (const float*)d_in[0];   // [B,T,D] fp32
    const float* wqkv = (const float*)d_in[1];   // [3D,D]  fp32
    const float* wout = (const float*)d_in[2];   // [D,D]   fp32

    short* kvbuf = (short*)d_out;                // K head-major + V dim-major bf16: 16MB
    short* qws   = (short*)d_ws;                 // Q scaled bf16 head-major; attn out in-place: 8MB
    float* out   = (float*)d_out;

    qkv_gemm<<<dim3(24, 32), 256, 0, stream>>>(x, wqkv, qws, kvbuf);
    attn<<<dim3(512), 256, 0, stream>>>(qws, kvbuf, qws);
    out_gemm<<<dim3(8, 32), 256, 0, stream>>>(qws, wout, out);
}

// Round 8
// 232.662 us; speedup vs baseline: 1.3715x; 1.3715x over previous
//
#include <hip/hip_runtime.h>
#include <hip/hip_bf16.h>

typedef __attribute__((ext_vector_type(8))) short shortx8;
typedef __attribute__((ext_vector_type(4))) float floatx4;
typedef __attribute__((ext_vector_type(4))) unsigned uintx4;
typedef __attribute__((ext_vector_type(2))) unsigned uintx2;

#define B_ 2
#define T_ 2048
#define D_ 1024
#define H_ 16
#define HD_ 64
#define SCALE 0.125f
#define SMAX 16.0f
#define FULLH ((size_t)B_ * H_ * T_ * HD_)

__device__ __forceinline__ short f2bf(float f) {
    union { float f; unsigned u; } v; v.f = f;
    unsigned r = v.u + 0x7FFFu + ((v.u >> 16) & 1u);
    return (short)(r >> 16);
}

__device__ __forceinline__ unsigned pk2(float x, float y) {
    union { __hip_bfloat162 h; unsigned u; } t;
    t.h = __float22bfloat162_rn(make_float2(x, y));
    return t.u;
}

// two float4 -> 8 bf16
__device__ __forceinline__ shortx8 cvt8(floatx4 a, floatx4 b) {
    uintx4 r = { pk2(a[0], a[1]), pk2(a[2], a[3]), pk2(b[0], b[1]), pk2(b[2], b[3]) };
    return __builtin_bit_cast(shortx8, r);
}

// Q/K/V projection, 64x64 tiles + register prefetch of next K-step.
// grid (48,64): sel=bx>>4 (0=q,1=k,2=v), h=bx&15; by -> m-tile.
// Q (scaled) & K head-major [b][h][t][d]; V dim-major [b][h][d][t].
__global__ __launch_bounds__(256) void qkv_gemm(const float* __restrict__ x,
                                                const float* __restrict__ wqkv,
                                                short* __restrict__ qout,
                                                short* __restrict__ kv) {
    __shared__ __align__(16) short As[64][72];
    __shared__ __align__(16) short Bs[64][72];

    const int tid = threadIdx.x;
    const int wv   = tid >> 6;
    const int l    = tid & 63;
    const int ln   = l & 15;
    const int quad = l >> 4;
    const int qd   = quad << 3;
    const int m0   = blockIdx.y * 64;
    const int sel  = blockIdx.x >> 4;
    const int h    = blockIdx.x & 15;
    const int nrow = sel * D_ + h * HD_;

    // staging geometry: thread covers rows sr0 & sr0+32 at col sc0 (8 wide)
    const int sr0 = tid >> 3, sc0 = (tid & 7) << 3, sr1 = sr0 + 32;

    floatx4 fa[4], fb[4];
    auto FETCH = [&](int k0) {
        const float* ap = &x[(size_t)(m0 + sr0) * D_ + k0 + sc0];
        fa[0] = *reinterpret_cast<const floatx4*>(ap);
        fa[1] = *reinterpret_cast<const floatx4*>(ap + 4);
        ap += (size_t)32 * D_;
        fa[2] = *reinterpret_cast<const floatx4*>(ap);
        fa[3] = *reinterpret_cast<const floatx4*>(ap + 4);
        const float* bp = &wqkv[(size_t)(nrow + sr0) * D_ + k0 + sc0];
        fb[0] = *reinterpret_cast<const floatx4*>(bp);
        fb[1] = *reinterpret_cast<const floatx4*>(bp + 4);
        bp += (size_t)32 * D_;
        fb[2] = *reinterpret_cast<const floatx4*>(bp);
        fb[3] = *reinterpret_cast<const floatx4*>(bp + 4);
    };

    floatx4 acc[4] = {};

    FETCH(0);
    for (int k0 = 0; k0 < D_; k0 += 64) {
        __syncthreads();
        *reinterpret_cast<shortx8*>(&As[sr0][sc0]) = cvt8(fa[0], fa[1]);
        *reinterpret_cast<shortx8*>(&As[sr1][sc0]) = cvt8(fa[2], fa[3]);
        *reinterpret_cast<shortx8*>(&Bs[sr0][sc0]) = cvt8(fb[0], fb[1]);
        *reinterpret_cast<shortx8*>(&Bs[sr1][sc0]) = cvt8(fb[2], fb[3]);
        __syncthreads();
        if (k0 + 64 < D_) FETCH(k0 + 64);

        const int mr = (wv << 4) + ln;
#pragma unroll
        for (int kk = 0; kk < 2; ++kk) {
            shortx8 a = *reinterpret_cast<const shortx8*>(&As[mr][kk * 32 + qd]);
#pragma unroll
            for (int nc = 0; nc < 4; ++nc) {
                shortx8 b = *reinterpret_cast<const shortx8*>(&Bs[nc * 16 + ln][kk * 32 + qd]);
                acc[nc] = __builtin_amdgcn_mfma_f32_16x16x32_bf16(a, b, acc[nc], 0, 0, 0);
            }
        }
    }

    const int bb = m0 >> 11;
    const int t0 = m0 & (T_ - 1);
    if (sel < 2) {
        short* dst = (sel == 0) ? qout : kv;
        const float sc = (sel == 0) ? SCALE : 1.0f;
#pragma unroll
        for (int r = 0; r < 4; ++r) {
            int t = t0 + (wv << 4) + (quad << 2) + r;
#pragma unroll
            for (int nc = 0; nc < 4; ++nc) {
                dst[((size_t)(bb * H_ + h) * T_ + t) * HD_ + nc * 16 + ln] = f2bf(acc[nc][r] * sc);
            }
        }
    } else {
        // V transposed [b][h][d][t] via LDS bounce (As dead after last barrier)
        __syncthreads();
#pragma unroll
        for (int r = 0; r < 4; ++r)
#pragma unroll
            for (int nc = 0; nc < 4; ++nc)
                As[nc * 16 + ln][(wv << 4) + (quad << 2) + r] = f2bf(acc[nc][r]);
        __syncthreads();
        const int d = tid >> 2, tseg = (tid & 3) << 4;
        short* vdst = kv + FULLH + ((size_t)(bb * H_ + h) * HD_ + d) * T_ + t0 + tseg;
        *reinterpret_cast<shortx8*>(vdst)     = *reinterpret_cast<const shortx8*>(&As[d][tseg]);
        *reinterpret_cast<shortx8*>(vdst + 8) = *reinterpret_cast<const shortx8*>(&As[d][tseg + 8]);
    }
}

// Flash attention (causal + ALiBi), fixed-max softmax, 64-query blocks (R6 proven).
// grid 1024: qb = 31-(bx&31) (heavy first), h=(bx>>5)&15, b=bx>>9.
__global__ __launch_bounds__(256, 4) void attn(const short* __restrict__ qws,
                                               const short* __restrict__ kv,
                                               short* ao) {
    __shared__ __align__(16) short Ks[64][72];
    __shared__ __align__(16) short Vt[64][72];      // Vt[d][key]
    __shared__ __align__(16) short Pt[4][64][20];   // per-wave [key][qrow+pad]

    const int tid = threadIdx.x;
    const int wv   = tid >> 6;
    const int l    = tid & 63;
    const int ln   = l & 15;
    const int quad = l >> 4;
    const int qd   = quad << 3;
    const int rowb = quad << 2;

    const int qb = 31 - (blockIdx.x & 31);
    const int h  = (blockIdx.x >> 5) & 15;
    const int b  = blockIdx.x >> 9;

    const float slope = exp2f(-(float)(h + 1) * (1.0f / 16.0f));
    const size_t koff = (size_t)(b * H_ + h) * T_ * HD_;
    const int q0 = qb * 64 + wv * 16;

    shortx8 qf[2];
#pragma unroll
    for (int kk = 0; kk < 2; ++kk)
        qf[kk] = *reinterpret_cast<const shortx8*>(&qws[koff + (size_t)(q0 + ln) * HD_ + kk * 32 + qd]);

    const int r0 = tid >> 3, c0 = (tid & 7) << 3, r1 = r0 + 32;
    const short* kbase = kv + koff;
    const short* vbase = kv + FULLH + koff;
    shortx8 kA, kB, vA, vB;
    auto FETCH = [&](int kb) {
        const short* kp = kbase + ((size_t)(kb * 64) << 6);
        kA = *reinterpret_cast<const shortx8*>(kp + ((size_t)r0 << 6) + c0);
        kB = *reinterpret_cast<const shortx8*>(kp + ((size_t)r1 << 6) + c0);
        const short* vp = vbase + kb * 64;
        vA = *reinterpret_cast<const shortx8*>(vp + ((size_t)r0 << 11) + c0);
        vB = *reinterpret_cast<const shortx8*>(vp + ((size_t)r1 << 11) + c0);
    };

    floatx4 oacc[4] = {};
    floatx4 lsum = {};
    const shortx8 ones = {16256, 16256, 16256, 16256, 16256, 16256, 16256, 16256}; // bf16 1.0
    const float base0 = -SMAX - slope * (float)(q0 + rowb);

    FETCH(0);
    for (int kb = 0; kb <= qb; ++kb) {
        __syncthreads();
        *reinterpret_cast<shortx8*>(&Ks[r0][c0]) = kA;
        *reinterpret_cast<shortx8*>(&Ks[r1][c0]) = kB;
        *reinterpret_cast<shortx8*>(&Vt[r0][c0]) = vA;
        *reinterpret_cast<shortx8*>(&Vt[r1][c0]) = vB;
        __syncthreads();
        if (kb < qb) FETCH(kb + 1);

        const bool diag = (kb == qb);
        const int ncmax = diag ? (wv + 1) : 4;
        const int kln = kb * 64 + ln;
        const float bb0 = slope * (float)kln + base0;

#pragma unroll
        for (int nc = 0; nc < 4; ++nc) {
            floatx4 s = {};
            if (nc < ncmax) {
#pragma unroll
                for (int kk = 0; kk < 2; ++kk) {
                    shortx8 bfr = *reinterpret_cast<const shortx8*>(&Ks[nc * 16 + ln][kk * 32 + qd]);
                    s = __builtin_amdgcn_mfma_f32_16x16x32_bf16(qf[kk], bfr, s, 0, 0, 0);
                }
            }
            float p[4];
#pragma unroll
            for (int r = 0; r < 4; ++r) {
                bool ok = (kln + nc * 16) <= (q0 + rowb + r);
                float e = __expf(s[r] + bb0 + slope * (float)(nc * 16 - r));
                p[r] = ok ? e : 0.0f;
            }
            uintx2 pkd = { pk2(p[0], p[1]), pk2(p[2], p[3]) };
            *reinterpret_cast<uintx2*>(&Pt[wv][nc * 16 + ln][rowb]) = pkd;
        }

#pragma unroll
        for (int kk = 0; kk < 2; ++kk) {
            if (diag && kk * 32 > wv * 16 + 15) continue;
            shortx8 pf;
#pragma unroll
            for (int j = 0; j < 8; ++j) pf[j] = Pt[wv][kk * 32 + qd + j][ln];
            lsum = __builtin_amdgcn_mfma_f32_16x16x32_bf16(pf, ones, lsum, 0, 0, 0);
#pragma unroll
            for (int nc = 0; nc < 4; ++nc) {
                shortx8 bfr = *reinterpret_cast<const shortx8*>(&Vt[nc * 16 + ln][kk * 32 + qd]);
                oacc[nc] = __builtin_amdgcn_mfma_f32_16x16x32_bf16(pf, bfr, oacc[nc], 0, 0, 0);
            }
        }
    }

#pragma unroll
    for (int r = 0; r < 4; ++r) {
        float inv = 1.0f / lsum[r];
        int t = q0 + rowb + r;
#pragma unroll
        for (int nc = 0; nc < 4; ++nc) {
            ao[koff + (size_t)t * HD_ + nc * 16 + ln] = f2bf(oacc[nc][r] * inv);
        }
    }
}

// Final projection, 64x64 tiles + register prefetch.
// out(fp32) = attn_out(bf16 head-major) @ w_out(fp32)^T
__global__ __launch_bounds__(256) void out_gemm(const short* __restrict__ A,
                                                const float* __restrict__ W,
                                                float* __restrict__ out) {
    __shared__ __align__(16) short As[64][72];
    __shared__ __align__(16) short Bs[64][72];

    const int tid = threadIdx.x;
    const int wv   = tid >> 6;
    const int l    = tid & 63;
    const int ln   = l & 15;
    const int quad = l >> 4;
    const int qd   = quad << 3;
    const int m0   = blockIdx.y * 64;
    const int n0   = blockIdx.x * 64;

    const int sr0 = tid >> 3, sc0 = (tid & 7) << 3, sr1 = sr0 + 32;

    shortx8 sa0, sa1;
    floatx4 fb[4];
    auto FETCH = [&](int k0) {
        const int h = k0 >> 6;
        {
            int m = m0 + sr0;
            int bb = m >> 11, t = m & (T_ - 1);
            sa0 = *reinterpret_cast<const shortx8*>(A + ((size_t)(bb * H_ + h) * T_ + t) * HD_ + sc0);
            m = m0 + sr1;
            bb = m >> 11; t = m & (T_ - 1);
            sa1 = *reinterpret_cast<const shortx8*>(A + ((size_t)(bb * H_ + h) * T_ + t) * HD_ + sc0);
        }
        const float* bp = &W[(size_t)(n0 + sr0) * D_ + k0 + sc0];
        fb[0] = *reinterpret_cast<const floatx4*>(bp);
        fb[1] = *reinterpret_cast<const floatx4*>(bp + 4);
        bp += (size_t)32 * D_;
        fb[2] = *reinterpret_cast<const floatx4*>(bp);
        fb[3] = *reinterpret_cast<const floatx4*>(bp + 4);
    };

    floatx4 acc[4] = {};

    FETCH(0);
    for (int k0 = 0; k0 < D_; k0 += 64) {
        __syncthreads();
        *reinterpret_cast<shortx8*>(&As[sr0][sc0]) = sa0;
        *reinterpret_cast<shortx8*>(&As[sr1][sc0]) = sa1;
        *reinterpret_cast<shortx8*>(&Bs[sr0][sc0]) = cvt8(fb[0], fb[1]);
        *reinterpret_cast<shortx8*>(&Bs[sr1][sc0]) = cvt8(fb[2], fb[3]);
        __syncthreads();
        if (k0 + 64 < D_) FETCH(k0 + 64);

        const int mr = (wv << 4) + ln;
#pragma unroll
        for (int kk = 0; kk < 2; ++kk) {
            shortx8 a = *reinterpret_cast<const shortx8*>(&As[mr][kk * 32 + qd]);
#pragma unroll
            for (int nc = 0; nc < 4; ++nc) {
                shortx8 b = *reinterpret_cast<const shortx8*>(&Bs[nc * 16 + ln][kk * 32 + qd]);
                acc[nc] = __builtin_amdgcn_mfma_f32_16x16x32_bf16(a, b, acc[nc], 0, 0, 0);
            }
        }
    }

#pragma unroll
    for (int r = 0; r < 4; ++r) {
        int m = m0 + (wv << 4) + (quad << 2) + r;
#pragma unroll
        for (int nc = 0; nc < 4; ++nc) {
            out[(size_t)m * D_ + n0 + nc * 16 + ln] = acc[nc][r];
        }
    }
}

extern "C" void kernel_launch(void* const* d_in, const int* in_sizes, int n_in,
                              void* d_out, int out_size, void* d_ws, size_t ws_size,
                              hipStream_t stream) {
    const float* x    = (const float*)d_in[0];   // [B,T,D] fp32
    const float* wqkv = (const float*)d_in[1];   // [3D,D]  fp32
    const float* wout = (const float*)d_in[2];   // [D,D]   fp32

    short* kvbuf = (short*)d_out;                // K head-major + V dim-major bf16: 16MB
    short* qws   = (short*)d_ws;                 // Q scaled bf16 head-major; attn out in-place: 8MB
    float* out   = (float*)d_out;

    qkv_gemm<<<dim3(48, 64), 256, 0, stream>>>(x, wqkv, qws, kvbuf);
    attn<<<dim3(1024), 256, 0, stream>>>(qws, kvbuf, qws);
    out_gemm<<<dim3(16, 64), 256, 0, stream>>>(qws, wout, out);
}

// Round 9
// 192.051 us; speedup vs baseline: 1.6615x; 1.2115x over previous
//
#include <hip/hip_runtime.h>
#include <hip/hip_bf16.h>

typedef __attribute__((ext_vector_type(8))) short shortx8;
typedef __attribute__((ext_vector_type(4))) float floatx4;
typedef __attribute__((ext_vector_type(4))) unsigned uintx4;
typedef __attribute__((ext_vector_type(2))) unsigned uintx2;

#define B_ 2
#define T_ 2048
#define D_ 1024
#define H_ 16
#define HD_ 64
#define SCALE 0.125f
#define SMAX 16.0f
#define FULLH ((size_t)B_ * H_ * T_ * HD_)

// async global->LDS, 16B per lane; LDS dest = wave-uniform base + lane*16
#define GLDS16(g, l) __builtin_amdgcn_global_load_lds( \
    (__attribute__((address_space(1))) void*)(g), \
    (__attribute__((address_space(3))) void*)(l), 16, 0, 0)

__device__ __forceinline__ short f2bf(float f) {
    union { float f; unsigned u; } v; v.f = f;
    unsigned r = v.u + 0x7FFFu + ((v.u >> 16) & 1u);
    return (short)(r >> 16);
}

__device__ __forceinline__ unsigned pk2(float x, float y) {
    union { __hip_bfloat162 h; unsigned u; } t;
    t.h = __float22bfloat162_rn(make_float2(x, y));
    return t.u;
}

__device__ __forceinline__ shortx8 cvt8(floatx4 a, floatx4 b) {
    uintx4 r = { pk2(a[0], a[1]), pk2(a[2], a[3]), pk2(b[0], b[1]), pk2(b[2], b[3]) };
    return __builtin_bit_cast(shortx8, r);
}

// ---------------- fp32 -> bf16 bulk convert ----------------
__global__ __launch_bounds__(256) void cvt_bf(const float* __restrict__ src,
                                              short* __restrict__ dst, int n8) {
    int i = blockIdx.x * 256 + threadIdx.x;
    if (i < n8) {
        const floatx4* p = reinterpret_cast<const floatx4*>(src) + (size_t)i * 2;
        *(reinterpret_cast<shortx8*>(dst) + i) = cvt8(p[0], p[1]);
    }
}

// ================= FAST PATH (bf16 inputs, m97-style) =================
// 128x128 tile, BK=64, global_load_lds staging with XOR chunk swizzle.
// LDS layout: slot(row, sc) holds logical chunk sc ^ (row&7); rows stride 64.

// Q/K/V projection. grid (24,32): n0g = bx*128 (sel = n0g>>10), m-tile by.
__global__ __launch_bounds__(256) void qkv_fast(const short* __restrict__ xbf,
                                                const short* __restrict__ wbf,
                                                short* __restrict__ qout,
                                                short* __restrict__ kv) {
    __shared__ __align__(16) short As[128 * 64];
    __shared__ __align__(16) short Bs[128 * 64];

    const int tid = threadIdx.x;
    const int wv = tid >> 6;
    const int l  = tid & 63;
    const int ln = l & 15;
    const int quad = l >> 4;
    const int rowb = quad << 2;
    const int wm = wv >> 1, wn = wv & 1;
    const int m0 = blockIdx.y * 128;
    const int n0g = blockIdx.x * 128;

    const int lr = l >> 3, lc = l & 7;
    const int gcol = (lc ^ lr) << 3;                 // swizzled source chunk
    const short* agp = xbf + (size_t)(m0 + wv * 32 + lr) * D_ + gcol;
    const short* bgp = wbf + (size_t)(n0g + wv * 32 + lr) * D_ + gcol;
    short* aldsb = As + wv * 32 * 64;
    short* bldsb = Bs + wv * 32 * 64;

    floatx4 acc[4][4] = {};

    for (int k0 = 0; k0 < D_; k0 += 64) {
        __syncthreads();
#pragma unroll
        for (int c = 0; c < 4; ++c) {
            GLDS16(agp + (size_t)(c * 8) * D_ + k0, aldsb + c * 512);
            GLDS16(bgp + (size_t)(c * 8) * D_ + k0, bldsb + c * 512);
        }
        __syncthreads();

#pragma unroll
        for (int kk = 0; kk < 2; ++kk) {
            const int csw = (kk << 2) + quad;
            const int sw = (csw ^ (ln & 7)) << 3;
            shortx8 af[4], bf[4];
#pragma unroll
            for (int i = 0; i < 4; ++i)
                af[i] = *reinterpret_cast<const shortx8*>(&As[((wm * 64 + i * 16 + ln) << 6) + sw]);
#pragma unroll
            for (int j = 0; j < 4; ++j)
                bf[j] = *reinterpret_cast<const shortx8*>(&Bs[((wn * 64 + j * 16 + ln) << 6) + sw]);
#pragma unroll
            for (int i = 0; i < 4; ++i)
#pragma unroll
                for (int j = 0; j < 4; ++j)
                    acc[i][j] = __builtin_amdgcn_mfma_f32_16x16x32_bf16(af[i], bf[j], acc[i][j], 0, 0, 0);
        }
    }

    const int sel = n0g >> 10;
    const int bb = m0 >> 11;
    const int t0w = (m0 + wm * 64) & (T_ - 1);
    const int h = ((n0g + wn * 64) >> 6) & 15;

    if (sel < 2) {
        short* dst = (sel == 0) ? qout : kv;
        const float sc = (sel == 0) ? SCALE : 1.0f;
        const size_t hb = (size_t)(bb * H_ + h) * T_;
#pragma unroll
        for (int i = 0; i < 4; ++i)
#pragma unroll
            for (int r = 0; r < 4; ++r) {
                int t = t0w + i * 16 + rowb + r;
#pragma unroll
                for (int j = 0; j < 4; ++j)
                    dst[(hb + t) * HD_ + j * 16 + ln] = f2bf(acc[i][j][r] * sc);
            }
    } else {
        // V -> dim-major [b][h][d][t], 2-pass per-wave LDS transpose (As/Bs dead)
        __syncthreads();
        short* tb = (wv < 2) ? (As + wv * 4096) : (Bs + (wv - 2) * 4096);  // 32x72 region
        short* vhead = kv + FULLH + (size_t)(bb * H_ + h) * HD_ * T_;
        const int dl = l & 31, th = (l >> 5) << 5;
#pragma unroll
        for (int p = 0; p < 2; ++p) {
#pragma unroll
            for (int i = 0; i < 4; ++i)
#pragma unroll
                for (int jj = 0; jj < 2; ++jj) {
                    int j = 2 * p + jj;
#pragma unroll
                    for (int r = 0; r < 4; ++r)
                        tb[(jj * 16 + ln) * 72 + i * 16 + rowb + r] = f2bf(acc[i][j][r]);
                }
            short* vd = vhead + (size_t)(p * 32 + dl) * T_ + t0w + th;
#pragma unroll
            for (int seg = 0; seg < 4; ++seg)
                *reinterpret_cast<shortx8*>(vd + seg * 8) =
                    *reinterpret_cast<const shortx8*>(&tb[dl * 72 + th + seg * 8]);
        }
    }
}

// Final projection. grid (8,32). A = attn out, bf16 head-major. W bf16 row-major.
__global__ __launch_bounds__(256) void out_fast(const short* __restrict__ Abf,
                                                const short* __restrict__ wbf,
                                                float* __restrict__ out) {
    __shared__ __align__(16) short As[128 * 64];
    __shared__ __align__(16) short Bs[128 * 64];

    const int tid = threadIdx.x;
    const int wv = tid >> 6;
    const int l  = tid & 63;
    const int ln = l & 15;
    const int quad = l >> 4;
    const int rowb = quad << 2;
    const int wm = wv >> 1, wn = wv & 1;
    const int m0 = blockIdx.y * 128;
    const int n0g = blockIdx.x * 128;

    const int lr = l >> 3, lc = l & 7;
    const int gcol = (lc ^ lr) << 3;
    const short* bgp = wbf + (size_t)(n0g + wv * 32 + lr) * D_ + gcol;
    short* aldsb = As + wv * 32 * 64;
    short* bldsb = Bs + wv * 32 * 64;

    size_t abase[4];
#pragma unroll
    for (int c = 0; c < 4; ++c) {
        int m = m0 + wv * 32 + c * 8 + lr;
        int bb2 = m >> 11, t = m & (T_ - 1);
        abase[c] = ((size_t)(bb2 * H_) * T_ + t) * HD_ + gcol;
    }

    floatx4 acc[4][4] = {};

    for (int k0 = 0; k0 < D_; k0 += 64) {
        const size_t hoff = (size_t)(k0 >> 6) * T_ * HD_;
        __syncthreads();
#pragma unroll
        for (int c = 0; c < 4; ++c) {
            GLDS16(Abf + abase[c] + hoff, aldsb + c * 512);
            GLDS16(bgp + (size_t)(c * 8) * D_ + k0, bldsb + c * 512);
        }
        __syncthreads();

#pragma unroll
        for (int kk = 0; kk < 2; ++kk) {
            const int csw = (kk << 2) + quad;
            const int sw = (csw ^ (ln & 7)) << 3;
            shortx8 af[4], bf[4];
#pragma unroll
            for (int i = 0; i < 4; ++i)
                af[i] = *reinterpret_cast<const shortx8*>(&As[((wm * 64 + i * 16 + ln) << 6) + sw]);
#pragma unroll
            for (int j = 0; j < 4; ++j)
                bf[j] = *reinterpret_cast<const shortx8*>(&Bs[((wn * 64 + j * 16 + ln) << 6) + sw]);
#pragma unroll
            for (int i = 0; i < 4; ++i)
#pragma unroll
                for (int j = 0; j < 4; ++j)
                    acc[i][j] = __builtin_amdgcn_mfma_f32_16x16x32_bf16(af[i], bf[j], acc[i][j], 0, 0, 0);
        }
    }

#pragma unroll
    for (int i = 0; i < 4; ++i)
#pragma unroll
        for (int r = 0; r < 4; ++r) {
            int m = m0 + wm * 64 + i * 16 + rowb + r;
#pragma unroll
            for (int j = 0; j < 4; ++j)
                out[(size_t)m * D_ + n0g + wn * 64 + j * 16 + ln] = acc[i][j][r];
        }
}

// ---------------- flash attention (shared by both paths) ----------------
// XCD-swizzled: blocks sharing (b,h) KV map to one XCD (dispatch ~ bx%8).
__global__ __launch_bounds__(256, 4) void attn(const short* __restrict__ qws,
                                               const short* __restrict__ kv,
                                               short* ao) {
    __shared__ __align__(16) short Ks[64][72];
    __shared__ __align__(16) short Vt[64][72];
    __shared__ __align__(16) short Pt[4][64][20];

    const int tid = threadIdx.x;
    const int wv   = tid >> 6;
    const int l    = tid & 63;
    const int ln   = l & 15;
    const int quad = l >> 4;
    const int qd   = quad << 3;
    const int rowb = quad << 2;

    const int xcd  = blockIdx.x & 7;
    const int slot = blockIdx.x >> 3;
    const int bh   = xcd * 4 + (slot & 3);   // 4 heads per XCD
    const int qb   = 31 - (slot >> 2);       // heavy tiles first
    const int h    = bh & 15;
    const int b    = bh >> 4;

    const float slope = exp2f(-(float)(h + 1) * (1.0f / 16.0f));
    const size_t koff = (size_t)(b * H_ + h) * T_ * HD_;
    const int q0 = qb * 64 + wv * 16;

    shortx8 qf[2];
#pragma unroll
    for (int kk = 0; kk < 2; ++kk)
        qf[kk] = *reinterpret_cast<const shortx8*>(&qws[koff + (size_t)(q0 + ln) * HD_ + kk * 32 + qd]);

    const int r0 = tid >> 3, c0 = (tid & 7) << 3, r1 = r0 + 32;
    const short* kbase = kv + koff;
    const short* vbase = kv + FULLH + koff;
    shortx8 kA, kB, vA, vB;
    auto FETCH = [&](int kb) {
        const short* kp = kbase + ((size_t)(kb * 64) << 6);
        kA = *reinterpret_cast<const shortx8*>(kp + ((size_t)r0 << 6) + c0);
        kB = *reinterpret_cast<const shortx8*>(kp + ((size_t)r1 << 6) + c0);
        const short* vp = vbase + kb * 64;
        vA = *reinterpret_cast<const shortx8*>(vp + ((size_t)r0 << 11) + c0);
        vB = *reinterpret_cast<const shortx8*>(vp + ((size_t)r1 << 11) + c0);
    };

    floatx4 oacc[4] = {};
    floatx4 lsum = {};
    const shortx8 ones = {16256, 16256, 16256, 16256, 16256, 16256, 16256, 16256};
    const float base0 = -SMAX - slope * (float)(q0 + rowb);

    FETCH(0);
    for (int kb = 0; kb <= qb; ++kb) {
        __syncthreads();
        *reinterpret_cast<shortx8*>(&Ks[r0][c0]) = kA;
        *reinterpret_cast<shortx8*>(&Ks[r1][c0]) = kB;
        *reinterpret_cast<shortx8*>(&Vt[r0][c0]) = vA;
        *reinterpret_cast<shortx8*>(&Vt[r1][c0]) = vB;
        __syncthreads();
        if (kb < qb) FETCH(kb + 1);

        const bool diag = (kb == qb);
        const int ncmax = diag ? (wv + 1) : 4;
        const int kln = kb * 64 + ln;
        const float bb0 = slope * (float)kln + base0;

#pragma unroll
        for (int nc = 0; nc < 4; ++nc) {
            floatx4 s = {};
            if (nc < ncmax) {
#pragma unroll
                for (int kk = 0; kk < 2; ++kk) {
                    shortx8 bfr = *reinterpret_cast<const shortx8*>(&Ks[nc * 16 + ln][kk * 32 + qd]);
                    s = __builtin_amdgcn_mfma_f32_16x16x32_bf16(qf[kk], bfr, s, 0, 0, 0);
                }
            }
            float p[4];
#pragma unroll
            for (int r = 0; r < 4; ++r) {
                bool ok = (kln + nc * 16) <= (q0 + rowb + r);
                float e = __expf(s[r] + bb0 + slope * (float)(nc * 16 - r));
                p[r] = ok ? e : 0.0f;
            }
            uintx2 pkd = { pk2(p[0], p[1]), pk2(p[2], p[3]) };
            *reinterpret_cast<uintx2*>(&Pt[wv][nc * 16 + ln][rowb]) = pkd;
        }

#pragma unroll
        for (int kk = 0; kk < 2; ++kk) {
            if (diag && kk * 32 > wv * 16 + 15) continue;
            shortx8 pf;
#pragma unroll
            for (int j = 0; j < 8; ++j) pf[j] = Pt[wv][kk * 32 + qd + j][ln];
            lsum = __builtin_amdgcn_mfma_f32_16x16x32_bf16(pf, ones, lsum, 0, 0, 0);
#pragma unroll
            for (int nc = 0; nc < 4; ++nc) {
                shortx8 bfr = *reinterpret_cast<const shortx8*>(&Vt[nc * 16 + ln][kk * 32 + qd]);
                oacc[nc] = __builtin_amdgcn_mfma_f32_16x16x32_bf16(pf, bfr, oacc[nc], 0, 0, 0);
            }
        }
    }

#pragma unroll
    for (int r = 0; r < 4; ++r) {
        float inv = 1.0f / lsum[r];
        int t = q0 + rowb + r;
#pragma unroll
        for (int nc = 0; nc < 4; ++nc)
            ao[koff + (size_t)t * HD_ + nc * 16 + ln] = f2bf(oacc[nc][r] * inv);
    }
}

// ================= FALLBACK PATH (R8, fp32 inputs) =================
__global__ __launch_bounds__(256) void qkv_slow(const float* __restrict__ x,
                                                const float* __restrict__ wqkv,
                                                short* __restrict__ qout,
                                                short* __restrict__ kv) {
    __shared__ __align__(16) short As[64][72];
    __shared__ __align__(16) short Bs[64][72];
    const int tid = threadIdx.x;
    const int wv = tid >> 6, l = tid & 63, ln = l & 15, quad = l >> 4, qd = quad << 3;
    const int m0 = blockIdx.y * 64;
    const int sel = blockIdx.x >> 4, h = blockIdx.x & 15;
    const int nrow = sel * D_ + h * HD_;
    const int sr0 = tid >> 3, sc0 = (tid & 7) << 3, sr1 = sr0 + 32;
    floatx4 fa[4], fb[4];
    auto FETCH = [&](int k0) {
        const float* ap = &x[(size_t)(m0 + sr0) * D_ + k0 + sc0];
        fa[0] = *reinterpret_cast<const floatx4*>(ap);
        fa[1] = *reinterpret_cast<const floatx4*>(ap + 4);
        ap += (size_t)32 * D_;
        fa[2] = *reinterpret_cast<const floatx4*>(ap);
        fa[3] = *reinterpret_cast<const floatx4*>(ap + 4);
        const float* bp = &wqkv[(size_t)(nrow + sr0) * D_ + k0 + sc0];
        fb[0] = *reinterpret_cast<const floatx4*>(bp);
        fb[1] = *reinterpret_cast<const floatx4*>(bp + 4);
        bp += (size_t)32 * D_;
        fb[2] = *reinterpret_cast<const floatx4*>(bp);
        fb[3] = *reinterpret_cast<const floatx4*>(bp + 4);
    };
    floatx4 acc[4] = {};
    FETCH(0);
    for (int k0 = 0; k0 < D_; k0 += 64) {
        __syncthreads();
        *reinterpret_cast<shortx8*>(&As[sr0][sc0]) = cvt8(fa[0], fa[1]);
        *reinterpret_cast<shortx8*>(&As[sr1][sc0]) = cvt8(fa[2], fa[3]);
        *reinterpret_cast<shortx8*>(&Bs[sr0][sc0]) = cvt8(fb[0], fb[1]);
        *reinterpret_cast<shortx8*>(&Bs[sr1][sc0]) = cvt8(fb[2], fb[3]);
        __syncthreads();
        if (k0 + 64 < D_) FETCH(k0 + 64);
        const int mr = (wv << 4) + ln;
#pragma unroll
        for (int kk = 0; kk < 2; ++kk) {
            shortx8 a = *reinterpret_cast<const shortx8*>(&As[mr][kk * 32 + qd]);
#pragma unroll
            for (int nc = 0; nc < 4; ++nc) {
                shortx8 b = *reinterpret_cast<const shortx8*>(&Bs[nc * 16 + ln][kk * 32 + qd]);
                acc[nc] = __builtin_amdgcn_mfma_f32_16x16x32_bf16(a, b, acc[nc], 0, 0, 0);
            }
        }
    }
    const int bb = m0 >> 11, t0 = m0 & (T_ - 1);
    if (sel < 2) {
        short* dst = (sel == 0) ? qout : kv;
        const float sc = (sel == 0) ? SCALE : 1.0f;
#pragma unroll
        for (int r = 0; r < 4; ++r) {
            int t = t0 + (wv << 4) + (quad << 2) + r;
#pragma unroll
            for (int nc = 0; nc < 4; ++nc)
                dst[((size_t)(bb * H_ + h) * T_ + t) * HD_ + nc * 16 + ln] = f2bf(acc[nc][r] * sc);
        }
    } else {
        __syncthreads();
#pragma unroll
        for (int r = 0; r < 4; ++r)
#pragma unroll
            for (int nc = 0; nc < 4; ++nc)
                As[nc * 16 + ln][(wv << 4) + (quad << 2) + r] = f2bf(acc[nc][r]);
        __syncthreads();
        const int d = tid >> 2, tseg = (tid & 3) << 4;
        short* vdst = kv + FULLH + ((size_t)(bb * H_ + h) * HD_ + d) * T_ + t0 + tseg;
        *reinterpret_cast<shortx8*>(vdst)     = *reinterpret_cast<const shortx8*>(&As[d][tseg]);
        *reinterpret_cast<shortx8*>(vdst + 8) = *reinterpret_cast<const shortx8*>(&As[d][tseg + 8]);
    }
}

__global__ __launch_bounds__(256) void out_slow(const short* __restrict__ A,
                                                const float* __restrict__ W,
                                                float* __restrict__ out) {
    __shared__ __align__(16) short As[64][72];
    __shared__ __align__(16) short Bs[64][72];
    const int tid = threadIdx.x;
    const int wv = tid >> 6, l = tid & 63, ln = l & 15, quad = l >> 4, qd = quad << 3;
    const int m0 = blockIdx.y * 64, n0 = blockIdx.x * 64;
    const int sr0 = tid >> 3, sc0 = (tid & 7) << 3, sr1 = sr0 + 32;
    shortx8 sa0, sa1;
    floatx4 fb[4];
    auto FETCH = [&](int k0) {
        const int h = k0 >> 6;
        int m = m0 + sr0;
        int bb = m >> 11, t = m & (T_ - 1);
        sa0 = *reinterpret_cast<const shortx8*>(A + ((size_t)(bb * H_ + h) * T_ + t) * HD_ + sc0);
        m = m0 + sr1; bb = m >> 11; t = m & (T_ - 1);
        sa1 = *reinterpret_cast<const shortx8*>(A + ((size_t)(bb * H_ + h) * T_ + t) * HD_ + sc0);
        const float* bp = &W[(size_t)(n0 + sr0) * D_ + k0 + sc0];
        fb[0] = *reinterpret_cast<const floatx4*>(bp);
        fb[1] = *reinterpret_cast<const floatx4*>(bp + 4);
        bp += (size_t)32 * D_;
        fb[2] = *reinterpret_cast<const floatx4*>(bp);
        fb[3] = *reinterpret_cast<const floatx4*>(bp + 4);
    };
    floatx4 acc[4] = {};
    FETCH(0);
    for (int k0 = 0; k0 < D_; k0 += 64) {
        __syncthreads();
        *reinterpret_cast<shortx8*>(&As[sr0][sc0]) = sa0;
        *reinterpret_cast<shortx8*>(&As[sr1][sc0]) = sa1;
        *reinterpret_cast<shortx8*>(&Bs[sr0][sc0]) = cvt8(fb[0], fb[1]);
        *reinterpret_cast<shortx8*>(&Bs[sr1][sc0]) = cvt8(fb[2], fb[3]);
        __syncthreads();
        if (k0 + 64 < D_) FETCH(k0 + 64);
        const int mr = (wv << 4) + ln;
#pragma unroll
        for (int kk = 0; kk < 2; ++kk) {
            shortx8 a = *reinterpret_cast<const shortx8*>(&As[mr][kk * 32 + qd]);
#pragma unroll
            for (int nc = 0; nc < 4; ++nc) {
                shortx8 b = *reinterpret_cast<const shortx8*>(&Bs[nc * 16 + ln][kk * 32 + qd]);
                acc[nc] = __builtin_amdgcn_mfma_f32_16x16x32_bf16(a, b, acc[nc], 0, 0, 0);
            }
        }
    }
#pragma unroll
    for (int r = 0; r < 4; ++r) {
        int m = m0 + (wv << 4) + (quad << 2) + r;
#pragma unroll
        for (int nc = 0; nc < 4; ++nc)
            out[(size_t)m * D_ + n0 + nc * 16 + ln] = acc[nc][r];
    }
}

extern "C" void kernel_launch(void* const* d_in, const int* in_sizes, int n_in,
                              void* d_out, int out_size, void* d_ws, size_t ws_size,
                              hipStream_t stream) {
    const float* x    = (const float*)d_in[0];
    const float* wqkv = (const float*)d_in[1];
    const float* wout = (const float*)d_in[2];

    short* kvbuf = (short*)d_out;    // K head-major + V dim-major bf16: 16MB
    float* out   = (float*)d_out;

    if (ws_size >= 23068672ULL) {    // 22 MiB fast path
        short* xbf  = (short*)d_ws;            // 4M shorts
        short* wbf  = xbf + 4 * 1024 * 1024;   // 3M shorts
        short* qws  = xbf + 7 * 1024 * 1024;   // 4M shorts (Q, then attn out in place)
        short* wobf = xbf;                     // overlays dead xbf after qkv_fast

        cvt_bf<<<2048, 256, 0, stream>>>(x, xbf, 524288);
        cvt_bf<<<1536, 256, 0, stream>>>(wqkv, wbf, 393216);
        qkv_fast<<<dim3(24, 32), 256, 0, stream>>>(xbf, wbf, qws, kvbuf);
        cvt_bf<<<512, 256, 0, stream>>>(wout, wobf, 131072);
        attn<<<dim3(1024), 256, 0, stream>>>(qws, kvbuf, qws);
        out_fast<<<dim3(8, 32), 256, 0, stream>>>(qws, wobf, out);
    } else {                          // proven R8 fallback
        short* qws = (short*)d_ws;
        qkv_slow<<<dim3(48, 64), 256, 0, stream>>>(x, wqkv, qws, kvbuf);
        attn<<<dim3(1024), 256, 0, stream>>>(qws, kvbuf, qws);
        out_slow<<<dim3(16, 64), 256, 0, stream>>>(qws, wout, out);
    }
}